// Round 1
// 646.212 us; speedup vs baseline: 1.0241x; 1.0241x over previous
//
#include <hip/hip_runtime.h>
#include <math.h>

typedef __bf16 bf16;
typedef bf16 bf16x4 __attribute__((ext_vector_type(4)));
typedef bf16 bf16x8 __attribute__((ext_vector_type(8)));
typedef float f32x4 __attribute__((ext_vector_type(4)));

#define T_TOK   1024
#define H_DIM   2048
#define I_DIM   1024
#define E_NUM   16
#define NPAIR_R 4096
#define NPAIR   5120

// async global->LDS, 16B per lane (dest = wave-uniform base + lane*16, linear)
typedef __attribute__((address_space(3))) unsigned int lds_uint;
typedef __attribute__((address_space(1))) const unsigned int gbl_uint;
__device__ __forceinline__ void gld16(const void* g, void* l) {
  __builtin_amdgcn_global_load_lds((gbl_uint*)g, (lds_uint*)l, 16, 0, 0);
}

// ---------------- router (+ fused x -> bf16 conversion) ----------------
__global__ __launch_bounds__(256) void router_kernel(
    const float* __restrict__ x, const float* __restrict__ gate_w,
    const float* __restrict__ e_bias, bf16* __restrict__ xb,
    int* __restrict__ topk_ids, float* __restrict__ topk_w,
    int* __restrict__ counts)
{
  int t = blockIdx.x;
  int tid = threadIdx.x;
  float acc[16];
#pragma unroll
  for (int e = 0; e < 16; ++e) acc[e] = 0.f;
  const float* xr = x + (size_t)t * H_DIM;
  bf16* xbr = xb + (size_t)t * H_DIM;
  for (int h = tid; h < H_DIM; h += 256) {
    float xv = xr[h];
    xbr[h] = (bf16)xv;   // fused conversion for the GEMM A operand
#pragma unroll
    for (int e = 0; e < 16; ++e) acc[e] += xv * gate_w[e * H_DIM + h];
  }
#pragma unroll
  for (int e = 0; e < 16; ++e) {
#pragma unroll
    for (int off = 32; off >= 1; off >>= 1)
      acc[e] += __shfl_down(acc[e], off, 64);
  }
  __shared__ float red[4][16];
  int lane = tid & 63, wave = tid >> 6;
  if (lane == 0) {
#pragma unroll
    for (int e = 0; e < 16; ++e) red[wave][e] = acc[e];
  }
  __syncthreads();
  if (tid == 0) {
    float scores[16], sb[16];
    for (int e = 0; e < 16; ++e) {
      float l = red[0][e] + red[1][e] + red[2][e] + red[3][e];
      float s = 1.f / (1.f + expf(-l));
      scores[e] = s;
      sb[e] = s + e_bias[e];
    }
    float gs[4];
    for (int g = 0; g < 4; ++g) {
      float b1 = -1e30f, b2 = -1e30f;
      for (int j = 0; j < 4; ++j) {
        float v = sb[g * 4 + j];
        if (v > b1) { b2 = b1; b1 = v; }
        else if (v > b2) b2 = v;
      }
      gs[g] = b1 + b2;
    }
    int g1 = 0; float bv = gs[0];
    for (int g = 1; g < 4; ++g) if (gs[g] > bv) { bv = gs[g]; g1 = g; }
    int g2 = -1; float bv2 = -1e30f;
    for (int g = 0; g < 4; ++g) if (g != g1 && gs[g] > bv2) { bv2 = gs[g]; g2 = g; }
    float tmp[16];
    for (int e = 0; e < 16; ++e) {
      int grp = e >> 2;
      tmp[e] = (grp == g1 || grp == g2) ? sb[e] : 0.0f;
    }
    bool used[16] = {false};
    int ids[4]; float wv[4]; float wsum = 0.f;
    for (int k = 0; k < 4; ++k) {
      int bi = 0; float bvv = -1e30f;
      for (int i = 0; i < 16; ++i)
        if (!used[i] && tmp[i] > bvv) { bvv = tmp[i]; bi = i; }
      used[bi] = true;
      ids[k] = bi; wv[k] = scores[bi]; wsum += scores[bi];
    }
    float inv = 1.f / wsum;
    for (int k = 0; k < 4; ++k) {
      topk_ids[t * 4 + k] = ids[k];
      topk_w[t * 4 + k] = wv[k] * inv;
      atomicAdd(&counts[ids[k]], 1);
    }
  }
}

// ---------------- offsets ----------------
__global__ void offsets_kernel(const int* __restrict__ counts, int* __restrict__ off)
{
  if (threadIdx.x == 0 && blockIdx.x == 0) {
    int s = 0;
    for (int e = 0; e < 16; ++e) { off[e] = s; s += counts[e]; }
    off[16] = s;
  }
}

// ---------------- scatter pairs ----------------
__global__ __launch_bounds__(256) void scatter_kernel(
    const int* __restrict__ topk_ids, const float* __restrict__ topk_w,
    const int* __restrict__ off, int* __restrict__ cursor,
    int* __restrict__ pair_token, float* __restrict__ pair_scale)
{
  int i = blockIdx.x * 256 + threadIdx.x;
  if (i < NPAIR_R) {
    int e = topk_ids[i];
    float w = topk_w[i];
    int pos = atomicAdd(&cursor[e], 1);
    int idx = off[e] + pos;
    pair_token[idx] = i >> 2;
    pair_scale[idx] = 2.5f * w;
  } else if (i < NPAIR) {
    pair_token[i] = i - NPAIR_R;
    pair_scale[i] = 1.0f;
  }
}

// ======================= gate_up GEMM, fused SiLU epilogue =======================
// Block tile: 128 pairs x (64 gate cols + 64 up cols), BK=32.
// A (bf16, gathered rows of xb) staged via global_load_lds, swizzle chunk^((r>>1)&3).
// B (fp32 weights) staged raw via global_load_lds, swizzle chunk^(r&7); cvt on frag read.
// LDS B rows 0..63 = gate rows nt*64+r ; rows 64..127 = up rows 1024+nt*64+(r-64).
__global__ __launch_bounds__(256, 3) void gateup_kernel(
    const bf16* __restrict__ xb, const float* __restrict__ w_gu,
    const float* __restrict__ s_wgu,
    const int* __restrict__ off, const int* __restrict__ pair_token,
    bf16* __restrict__ a_buf)
{
  const int nt = blockIdx.x;   // 0..15 over I in 64-col chunks
  const int mt = blockIdx.y;   // 0..7
  const int e  = blockIdx.z;   // 0..16 (16 = shared)
  const int poff = (e < 16) ? off[e]     : NPAIR_R;
  const int pend = (e < 16) ? off[e + 1] : NPAIR;
  const int cnt  = pend - poff;
  if (mt * 128 >= cnt) return;
  const float* __restrict__ B = (e < 16) ? (w_gu + (size_t)e * 2 * I_DIM * H_DIM) : s_wgu;

  __shared__ __align__(16) bf16  As[2][128 * 32];
  __shared__ __align__(16) float Bs[2][128 * 32];

  const int tid = threadIdx.x;
  const int lane = tid & 63;
  const int wave = tid >> 6;
  const int wm = wave >> 1, wn = wave & 1;
  const int c0 = lane >> 4;     // k-chunk (8 elems)
  const int fr = lane & 15;

  // staging sources (fixed per thread; only k0 advances)
  const bf16* aptr[2];
#pragma unroll
  for (int s = 0; s < 2; ++s) {
    int idx = s * 256 + tid;
    int ar = idx >> 2, ach = idx & 3;
    int sch = ach ^ ((ar >> 1) & 3);
    int p = poff + mt * 128 + ar;            // < NPAIR always
    aptr[s] = xb + (size_t)pair_token[p] * H_DIM + sch * 8;
  }
  const float* bptr[4];
#pragma unroll
  for (int s = 0; s < 4; ++s) {
    int idx = s * 256 + tid;
    int br = idx >> 3, bch = idx & 7;
    int sch = bch ^ (br & 7);
    int rg = nt * 64 + br + (br >= 64 ? 960 : 0);   // gate rows / up rows
    bptr[s] = B + (size_t)rg * H_DIM + sch * 4;
  }
  // fragment read byte offsets (swizzled, fixed per thread)
  int a_off[4];
#pragma unroll
  for (int mi = 0; mi < 4; ++mi) {
    int ar = wm * 64 + mi * 16 + fr;
    a_off[mi] = ar * 64 + ((c0 ^ ((ar >> 1) & 3)) << 4);
  }
  int b_off[4];
#pragma unroll
  for (int ni = 0; ni < 4; ++ni) {
    int br = wn * 32 + (ni & 1) * 16 + fr + (ni >> 1) * 64;
    b_off[ni] = br * 128 + (((2 * c0) ^ (br & 7)) << 4);
  }

  f32x4 acc[4][4];
  f32x4 zz = {0.f, 0.f, 0.f, 0.f};
#pragma unroll
  for (int mi = 0; mi < 4; ++mi)
#pragma unroll
    for (int ni = 0; ni < 4; ++ni) acc[mi][ni] = zz;

  const int ldso = tid * 16;
  // prologue: stage k=0 into buf 0
#pragma unroll
  for (int s = 0; s < 2; ++s)
    gld16(aptr[s], (char*)(&As[0][0]) + s * 4096 + ldso);
#pragma unroll
  for (int s = 0; s < 4; ++s)
    gld16(bptr[s], (char*)(&Bs[0][0]) + s * 4096 + ldso);
  __syncthreads();

  int cur = 0;
  const int NT = H_DIM / 32;
  for (int t = 0; t < NT; ++t) {
    if (t + 1 < NT) {
      const int k0 = (t + 1) * 32;
#pragma unroll
      for (int s = 0; s < 2; ++s)
        gld16(aptr[s] + k0, (char*)(&As[cur ^ 1][0]) + s * 4096 + ldso);
#pragma unroll
      for (int s = 0; s < 4; ++s)
        gld16(bptr[s] + k0, (char*)(&Bs[cur ^ 1][0]) + s * 4096 + ldso);
    }
    const char* Ab = (const char*)(&As[cur][0]);
    const char* Bb = (const char*)(&Bs[cur][0]);
    bf16x8 af[4], bv[4];
#pragma unroll
    for (int mi = 0; mi < 4; ++mi)
      af[mi] = *(const bf16x8*)(Ab + a_off[mi]);
#pragma unroll
    for (int ni = 0; ni < 4; ++ni) {
      f32x4 x0 = *(const f32x4*)(Bb + b_off[ni]);
      f32x4 x1 = *(const f32x4*)(Bb + (b_off[ni] ^ 16));
      bf16x8 b;
      b[0] = (bf16)x0[0]; b[1] = (bf16)x0[1]; b[2] = (bf16)x0[2]; b[3] = (bf16)x0[3];
      b[4] = (bf16)x1[0]; b[5] = (bf16)x1[1]; b[6] = (bf16)x1[2]; b[7] = (bf16)x1[3];
      bv[ni] = b;
    }
#pragma unroll
    for (int mi = 0; mi < 4; ++mi)
#pragma unroll
      for (int ni = 0; ni < 4; ++ni)
        acc[mi][ni] = __builtin_amdgcn_mfma_f32_16x16x32_bf16(af[mi], bv[ni], acc[mi][ni], 0, 0, 0);
    __syncthreads();
    cur ^= 1;
  }

  // epilogue: silu(gate)*up -> a_buf (bf16), gate=ni{0,1}, up=ni{2,3}
#pragma unroll
  for (int mi = 0; mi < 4; ++mi) {
#pragma unroll
    for (int reg = 0; reg < 4; ++reg) {
      int r = wm * 64 + mi * 16 + c0 * 4 + reg;
      int rl = mt * 128 + r;
      if (rl < cnt) {
        size_t p = (size_t)(poff + rl);
        bf16* orow = a_buf + p * I_DIM + nt * 64 + wn * 32 + fr;
#pragma unroll
        for (int ni = 0; ni < 2; ++ni) {
          float g = acc[mi][ni][reg];
          float u = acc[mi][ni + 2][reg];
          float sg = g / (1.f + expf(-g));
          orow[ni * 16] = (bf16)(sg * u);
        }
      }
    }
  }
}

// ======================= down GEMM + scaled atomic scatter =======================
__global__ __launch_bounds__(256, 3) void down_kernel(
    const bf16* __restrict__ a_buf, const float* __restrict__ w_dn,
    const float* __restrict__ s_wdn,
    const int* __restrict__ off, const int* __restrict__ pair_token,
    const float* __restrict__ pair_scale, float* __restrict__ out)
{
  const int nt = blockIdx.x;   // 0..15 over H in 128-col chunks
  const int mt = blockIdx.y;   // 0..7
  const int e  = blockIdx.z;   // 0..16
  const int poff = (e < 16) ? off[e]     : NPAIR_R;
  const int pend = (e < 16) ? off[e + 1] : NPAIR;
  const int cnt  = pend - poff;
  if (mt * 128 >= cnt) return;
  const float* __restrict__ B = (e < 16) ? (w_dn + (size_t)e * H_DIM * I_DIM) : s_wdn;

  __shared__ __align__(16) bf16  As[2][128 * 32];
  __shared__ __align__(16) float Bs[2][128 * 32];

  const int tid = threadIdx.x;
  const int lane = tid & 63;
  const int wave = tid >> 6;
  const int wm = wave >> 1, wn = wave & 1;
  const int c0 = lane >> 4;
  const int fr = lane & 15;

  const bf16* aptr[2];
#pragma unroll
  for (int s = 0; s < 2; ++s) {
    int idx = s * 256 + tid;
    int ar = idx >> 2, ach = idx & 3;
    int sch = ach ^ ((ar >> 1) & 3);
    int p = poff + mt * 128 + ar;            // < NPAIR always
    aptr[s] = a_buf + (size_t)p * I_DIM + sch * 8;
  }
  const float* bptr[4];
#pragma unroll
  for (int s = 0; s < 4; ++s) {
    int idx = s * 256 + tid;
    int br = idx >> 3, bch = idx & 7;
    int sch = bch ^ (br & 7);
    bptr[s] = B + (size_t)(nt * 128 + br) * I_DIM + sch * 4;
  }
  int a_off[4];
#pragma unroll
  for (int mi = 0; mi < 4; ++mi) {
    int ar = wm * 64 + mi * 16 + fr;
    a_off[mi] = ar * 64 + ((c0 ^ ((ar >> 1) & 3)) << 4);
  }
  int b_off[4];
#pragma unroll
  for (int ni = 0; ni < 4; ++ni) {
    int br = wn * 64 + ni * 16 + fr;
    b_off[ni] = br * 128 + (((2 * c0) ^ (br & 7)) << 4);
  }

  f32x4 acc[4][4];
  f32x4 zz = {0.f, 0.f, 0.f, 0.f};
#pragma unroll
  for (int mi = 0; mi < 4; ++mi)
#pragma unroll
    for (int ni = 0; ni < 4; ++ni) acc[mi][ni] = zz;

  const int ldso = tid * 16;
#pragma unroll
  for (int s = 0; s < 2; ++s)
    gld16(aptr[s], (char*)(&As[0][0]) + s * 4096 + ldso);
#pragma unroll
  for (int s = 0; s < 4; ++s)
    gld16(bptr[s], (char*)(&Bs[0][0]) + s * 4096 + ldso);
  __syncthreads();

  int cur = 0;
  const int NT = I_DIM / 32;
  for (int t = 0; t < NT; ++t) {
    if (t + 1 < NT) {
      const int k0 = (t + 1) * 32;
#pragma unroll
      for (int s = 0; s < 2; ++s)
        gld16(aptr[s] + k0, (char*)(&As[cur ^ 1][0]) + s * 4096 + ldso);
#pragma unroll
      for (int s = 0; s < 4; ++s)
        gld16(bptr[s] + k0, (char*)(&Bs[cur ^ 1][0]) + s * 4096 + ldso);
    }
    const char* Ab = (const char*)(&As[cur][0]);
    const char* Bb = (const char*)(&Bs[cur][0]);
    bf16x8 af[4], bv[4];
#pragma unroll
    for (int mi = 0; mi < 4; ++mi)
      af[mi] = *(const bf16x8*)(Ab + a_off[mi]);
#pragma unroll
    for (int ni = 0; ni < 4; ++ni) {
      f32x4 x0 = *(const f32x4*)(Bb + b_off[ni]);
      f32x4 x1 = *(const f32x4*)(Bb + (b_off[ni] ^ 16));
      bf16x8 b;
      b[0] = (bf16)x0[0]; b[1] = (bf16)x0[1]; b[2] = (bf16)x0[2]; b[3] = (bf16)x0[3];
      b[4] = (bf16)x1[0]; b[5] = (bf16)x1[1]; b[6] = (bf16)x1[2]; b[7] = (bf16)x1[3];
      bv[ni] = b;
    }
#pragma unroll
    for (int mi = 0; mi < 4; ++mi)
#pragma unroll
      for (int ni = 0; ni < 4; ++ni)
        acc[mi][ni] = __builtin_amdgcn_mfma_f32_16x16x32_bf16(af[mi], bv[ni], acc[mi][ni], 0, 0, 0);
    __syncthreads();
    cur ^= 1;
  }

  const int colb = nt * 128 + wn * 64;
#pragma unroll
  for (int mi = 0; mi < 4; ++mi) {
#pragma unroll
    for (int reg = 0; reg < 4; ++reg) {
      int r = wm * 64 + mi * 16 + c0 * 4 + reg;
      int rl = mt * 128 + r;
      if (rl < cnt) {
        int p = poff + rl;
        int tok = pair_token[p];
        float sc = pair_scale[p];
        float* orow = out + (size_t)tok * H_DIM + colb + fr;
#pragma unroll
        for (int ni = 0; ni < 4; ++ni)
          atomicAdd(&orow[ni * 16], acc[mi][ni][reg] * sc);
      }
    }
  }
}

// ---------------- launch ----------------
extern "C" void kernel_launch(void* const* d_in, const int* in_sizes, int n_in,
                              void* d_out, int out_size, void* d_ws, size_t ws_size,
                              hipStream_t stream)
{
  const float* x     = (const float*)d_in[0];
  const float* gatew = (const float*)d_in[1];
  const float* ebias = (const float*)d_in[2];
  const float* w_gu  = (const float*)d_in[3];
  const float* w_dn  = (const float*)d_in[4];
  const float* s_wgu = (const float*)d_in[5];
  const float* s_wdn = (const float*)d_in[6];
  float* out = (float*)d_out;

  char* ws = (char*)d_ws;
  int*   off        = (int*)(ws + 0);        // 32 ints
  int*   counts     = (int*)(ws + 128);      // 16 ints
  int*   cursor     = (int*)(ws + 192);      // 16 ints
  int*   topk_ids   = (int*)(ws + 256);      // 4096 ints
  float* topk_w     = (float*)(ws + 16640);  // 4096 floats
  int*   pair_token = (int*)(ws + 33024);    // 5120 ints
  float* pair_scale = (float*)(ws + 53504);  // 5120 floats
  bf16*  x_bf16     = (bf16*)(ws + 73984);   // 1024*2048 bf16 = 4,194,304 B
  bf16*  a_buf      = (bf16*)(ws + 73984 + 4194304);  // 5120*1024 bf16 = 10,485,760 B

  hipMemsetAsync(out, 0, (size_t)T_TOK * H_DIM * sizeof(float), stream);
  hipMemsetAsync(ws + 128, 0, 128, stream);  // counts + cursor

  router_kernel<<<T_TOK, 256, 0, stream>>>(x, gatew, ebias, x_bf16, topk_ids, topk_w, counts);
  offsets_kernel<<<1, 64, 0, stream>>>(counts, off);
  scatter_kernel<<<NPAIR / 256, 256, 0, stream>>>(topk_ids, topk_w, off, cursor,
                                                  pair_token, pair_scale);
  dim3 g1(16, 8, 17);
  gateup_kernel<<<g1, 256, 0, stream>>>(x_bf16, w_gu, s_wgu, off, pair_token, a_buf);
  dim3 g2(16, 8, 17);
  down_kernel<<<g2, 256, 0, stream>>>(a_buf, w_dn, s_wdn, off, pair_token, pair_scale, out);
}